// Round 2
// baseline (597.247 us; speedup 1.0000x reference)
//
#include <hip/hip_runtime.h>

#define NL 21
#define NC 256
#define NB 64
#define PPB 16       // planes per block (consecutive c, same (feat,b) since 16|256)

// ---- LDS-free gather pooling kernel ----
// grid.x = 2*64*256/PPB = 2048 blocks; each handles PPB consecutive planes.
// Per wave: 4 landmark slots x 16 lanes (4x4 sub-tile, 3x3 taps -> <=12x12 window).
// 2 passes cover 21 landmarks. Offsets clamped into the window + 0/1 masks,
// precomputed once: the plane loop is 18 loads (SGPR base + invariant VGPR
// offsets) + 18 fmac + 8 width-16 shuffles. No __shared__, no barriers.
__global__ __launch_bounds__(256) void pool_kernel(
    const float* __restrict__ f1, const float* __restrict__ f2,
    const float* __restrict__ pre1, const float* __restrict__ pre2,
    float* __restrict__ part1, float* __restrict__ part2) {
    const int p0   = blockIdx.x * PPB;       // first plane id
    const int feat = p0 >> 14;               // 16384 planes per feature
    const int b    = (p0 >> 8) & 63;
    const int c0   = p0 & 255;
    const float* __restrict__ base = (feat ? f2 : f1) + (size_t)(b * NC + c0) * 4096;
    const float* __restrict__ pre  = feat ? pre2 : pre1;
    float* __restrict__ outp       = (feat ? part2 : part1) + (size_t)b * NL * NC + c0;

    const int t    = threadIdx.x;
    const int slot = t >> 4;                 // landmark slot 0..15
    const int li   = t & 15;                 // lane in 16-group
    const int ro   = li >> 2;                // row sub-offset 0..3
    const int co   = li & 3;                 // col sub-offset 0..3

    int   boff[2][9];                        // byte offsets into a plane
    float msk[2][9];                         // 0/1 window masks
    float inv[2];
    int   lrow[2];                           // landmark index
    bool  valid[2];

#pragma unroll
    for (int pp = 0; pp < 2; ++pp) {
        const int l = slot + 16 * pp;
        valid[pp] = (l < NL);
        const int lc = valid[pp] ? l : NL - 1;
        lrow[pp] = lc;
        // faithful quirks: x -> H axis (rows), y -> W axis (cols);
        // trunc casts after clamp; inclusive divisor, exclusive sum window
        const float x = pre[(b * NL + lc) * 2 + 0];
        const float y = pre[(b * NL + lc) * 2 + 1];
        const int down  = (int)fmaxf(y - 6.0f, 0.0f);
        const int left  = (int)fmaxf(x - 6.0f, 0.0f);
        const int upper = (int)fminf(y + 6.0f, 63.0f);
        const int right = (int)fminf(x + 6.0f, 63.0f);
        const int RL = right - left;         // exclusive row count, 6..12
        const int UD = upper - down;         // exclusive col count, 6..12
        inv[pp] = 1.0f / (float)((UD + 1) * (RL + 1));
        int rowc[3], colc[3];
        float rm[3], cm[3];
#pragma unroll
        for (int p = 0; p < 3; ++p) {
            const int a = ro + 4 * p;        // row offset within window, 0..11
            rm[p]   = (valid[pp] && a < RL) ? 1.0f : 0.0f;
            rowc[p] = left + (a < RL ? a : RL - 1);   // clamp keeps addr in-plane
            const int c = co + 4 * p;        // col offset within window, 0..11
            cm[p]   = (c < UD) ? 1.0f : 0.0f;
            colc[p] = down + (c < UD ? c : UD - 1);
        }
#pragma unroll
        for (int p = 0; p < 3; ++p)
#pragma unroll
            for (int q = 0; q < 3; ++q) {
                boff[pp][p * 3 + q] = ((rowc[p] << 6) + colc[q]) << 2;
                msk[pp][p * 3 + q]  = rm[p] * cm[q];
            }
    }

    for (int i = 0; i < PPB; ++i) {
        const char* __restrict__ pc = (const char*)base + (size_t)i * 16384;
        float s0 = 0.0f, s1 = 0.0f;
#pragma unroll
        for (int k = 0; k < 9; ++k)
            s0 = fmaf(msk[0][k], *(const float*)(pc + boff[0][k]), s0);
#pragma unroll
        for (int k = 0; k < 9; ++k)
            s1 = fmaf(msk[1][k], *(const float*)(pc + boff[1][k]), s1);
#pragma unroll
        for (int o = 8; o > 0; o >>= 1) {
            s0 += __shfl_xor(s0, o, 16);
            s1 += __shfl_xor(s1, o, 16);
        }
        if (li == 0) {
            outp[lrow[0] * NC + i] = s0 * inv[0];
            if (valid[1]) outp[lrow[1] * NC + i] = s1 * inv[1];
        }
    }
}

// ---- reduce kernel: [64][21][256] -> [21][256] + EMA, per feature ----
// grid.x = 2*21 = 42 blocks, 256 threads
__global__ __launch_bounds__(256) void reduce_kernel(
    const float* __restrict__ part1, const float* __restrict__ part2,
    const float* __restrict__ fea1, const float* __restrict__ fea2,
    float* __restrict__ sc /* [2][21][256] */) {
    const int f = blockIdx.x / NL;
    const int l = blockIdx.x - f * NL;
    const int c = threadIdx.x;
    const float* __restrict__ part = f ? part2 : part1;
    const float* __restrict__ fea  = f ? fea2 : fea1;
    float s = 0.0f;
    for (int b = 0; b < NB; ++b) s += part[((size_t)b * NL + l) * NC + c];
    sc[(f * NL + l) * NC + c] = 0.999f * (s * (1.0f / 64.0f)) + 0.001f * fea[l * NC + c];
}

// ---- finish kernel: one wave per row, shuffle-only reductions ----
__global__ __launch_bounds__(256) void finish_kernel(const float* __restrict__ sc,
                                                     float* __restrict__ out) {
    const int t = threadIdx.x;
    const int wave = t >> 6, lane = t & 63;
    __shared__ float rowkl[NL];

    for (int l = wave; l < NL; l += 4) {
        const float* __restrict__ r1 = &sc[l * NC];            // fea_c1 row
        const float* __restrict__ r2 = &sc[(NL + l) * NC];     // fea_c2 row
        float x1[4], x2[4];
#pragma unroll
        for (int j = 0; j < 4; ++j) { x1[j] = r1[lane + 64 * j]; x2[j] = r2[lane + 64 * j]; }

        float m  = fmaxf(fmaxf(x1[0], x1[1]), fmaxf(x1[2], x1[3]));
        float s2 = x2[0] + x2[1] + x2[2] + x2[3];
#pragma unroll
        for (int o = 32; o > 0; o >>= 1) {
            m  = fmaxf(m, __shfl_xor(m, o, 64));
            s2 += __shfl_xor(s2, o, 64);
        }
        float es = 0.0f;
#pragma unroll
        for (int j = 0; j < 4; ++j) es += __expf(x1[j] - m);
#pragma unroll
        for (int o = 32; o > 0; o >>= 1) es += __shfl_xor(es, o, 64);
        const float logZ = m + logf(es);
        const float inv_s2 = 1.0f / s2;

        float kl = 0.0f;
#pragma unroll
        for (int j = 0; j < 4; ++j) {
            const float q = x2[j] * inv_s2;
            if (q > 0.0f) kl += q * (logf(q) - (x1[j] - logZ));
        }
#pragma unroll
        for (int o = 32; o > 0; o >>= 1) kl += __shfl_xor(kl, o, 64);
        if (lane == 0) rowkl[l] = kl;
    }
    __syncthreads();
    if (t == 0) {
        float tot = 0.0f;
        for (int l = 0; l < NL; ++l) tot += rowkl[l];
        out[0] = tot / 21.0f;
    }
}

extern "C" void kernel_launch(void* const* d_in, const int* in_sizes, int n_in,
                              void* d_out, int out_size, void* d_ws, size_t ws_size,
                              hipStream_t stream) {
    const float* f1   = (const float*)d_in[0];
    const float* f2   = (const float*)d_in[1];
    const float* pre1 = (const float*)d_in[2];
    const float* pre2 = (const float*)d_in[3];
    const float* fea1 = (const float*)d_in[4];
    const float* fea2 = (const float*)d_in[5];
    float* out = (float*)d_out;

    float* part1 = (float*)d_ws;                       // [64][21][256]
    float* part2 = part1 + (size_t)NB * NL * NC;       // [64][21][256]
    float* sc    = part2 + (size_t)NB * NL * NC;       // [2][21][256]

    pool_kernel<<<dim3(2 * NB * NC / PPB), 256, 0, stream>>>(f1, f2, pre1, pre2, part1, part2);
    reduce_kernel<<<dim3(2 * NL), 256, 0, stream>>>(part1, part2, fea1, fea2, sc);
    finish_kernel<<<1, 256, 0, stream>>>(sc, out);
}